// Round 15
// baseline (285.439 us; speedup 1.0000x reference)
//
#include <hip/hip_runtime.h>

// Round 15: DIAGNOSTIC round. Real kernel = R11 verbatim (passes, 30.2us),
// plus three x4-repeated probe kernels writing to d_ws so they appear in the
// rocprof top-5 with counters (they exceed the 75us fillBuffer dispatches):
//   probe_full  = R11 body x4           -> steady-state cost + VALUBusy
//   probe_chain = chain only (no loads) -> arithmetic-chain component
//   probe_load  = loads only (no chain) -> gather/memory component
// Probes are rep-perturbed to block cross-rep CSE; they write only d_ws.

constexpr int Bc = 512, Tc = 512, Cc = 128, Lc = 48;
constexpr double DEPS = 1e-7;
constexpr float FNEG = -1e30f;
constexpr float LN2F = 0.69314718055994530942f;

#define DPP_WAVE_SHR1 0x138
#define DPP_WAVE_SHL1 0x130

__device__ __forceinline__ double dpp64_shr1(double x) {
    long long u = __double_as_longlong(x);
    int a = __builtin_amdgcn_update_dpp(0, (int)u,         DPP_WAVE_SHR1, 0xF, 0xF, false);
    int b = __builtin_amdgcn_update_dpp(0, (int)(u >> 32), DPP_WAVE_SHR1, 0xF, 0xF, false);
    return __longlong_as_double(((long long)b << 32) | (unsigned int)a);
}
__device__ __forceinline__ double dpp64_shl1(double x) {
    long long u = __double_as_longlong(x);
    int a = __builtin_amdgcn_update_dpp(0, (int)u,         DPP_WAVE_SHL1, 0xF, 0xF, false);
    int b = __builtin_amdgcn_update_dpp(0, (int)(u >> 32), DPP_WAVE_SHL1, 0xF, 0xF, false);
    return __longlong_as_double(((long long)b << 32) | (unsigned int)a);
}
__device__ __forceinline__ float lae2(float a, float b) {
    float m = fmaxf(a, b);
    float d = fabsf(a - b);
    return m + __log2f(1.0f + __builtin_amdgcn_exp2f(-d));
}
__device__ __forceinline__ float blankpf(float praw) {
    return __uint_as_float((unsigned)
        __builtin_amdgcn_readlane(__float_as_uint(praw), 63));
}
__device__ __forceinline__ float log2d(double x) {
    if (!(x > 0.0)) return FNEG;
    long long u = __double_as_longlong(x);
    int e = (int)((u >> 52) & 0x7FF);
    if (e == 0) return FNEG;
    double m = __longlong_as_double((u & 0x000FFFFFFFFFFFFFLL) | 0x3FF0000000000000LL);
    return __log2f((float)m) + (float)(e - 1023);
}
__device__ __forceinline__ float synthp(int k, int lane, int rep) {
    unsigned h = (unsigned)k * 2654435761u + (unsigned)lane * 40503u + (unsigned)rep * 97u;
    return __uint_as_float(0x3B800000u | (h & 0x003FFFFFu));  // [2^-8, 2^-7)
}

// ---------------------------------------------------------------- real kernel
__global__ __launch_bounds__(128)
void ctc_fb_kernel(const int* __restrict__ y_true,
                   const float* __restrict__ y_pred,
                   float* __restrict__ out) {
    const int b = blockIdx.x;
    const int lane = threadIdx.x & 63;
    const int wave = threadIdx.x >> 6;

    const float* yb = y_pred + (size_t)b * Tc * Cc;

    const int lab = (lane < Lc) ? y_true[b * Lc + lane] : (Cc - 1);
    const int labm1 = __builtin_amdgcn_ds_bpermute(((lane + 63) & 63) << 2, lab);
    const int labp1 = __builtin_amdgcn_ds_bpermute(((lane + 1) & 63) << 2, lab);
    const bool skip  = (lab != (Cc - 1)) && (lab != labm1);
    const bool skipN = (labp1 != (Cc - 1)) && (labp1 != lab);
    const bool validhi = (lane < Lc);
    const bool lane0 = (lane == 0);

    __shared__ double sblo[64], sbhi[64];
    __shared__ int sbc[64];

    double lo = 0.0, hi = 0.0;
    int c = 0;

    auto renorm = [&]() {
        double mx = fmax(lo, hi);
        #pragma unroll
        for (int mk = 1; mk < 64; mk <<= 1)
            mx = fmax(mx, __shfl_xor(mx, mk, 64));
        int e = (int)((__double_as_longlong(mx) >> 52) & 0x7FF) - 1023;
        double sc = __longlong_as_double((long long)(1023 - e) << 52);
        lo *= sc; hi *= sc;
        c += e;
    };

    if (wave == 0) {
        auto dostep = [&](float praw) {
            double pb = (double)blankpf(praw) + DEPS;
            double ph = validhi ? ((double)praw + DEPS) : 0.0;
            double sh = dpp64_shr1(hi);
            double a3 = skip ? sh : 0.0;
            double nlo = (lo + sh) * pb;
            double nhi = (hi + lo + a3) * ph;
            lo = nlo; hi = nhi;
        };
        float pf[32];
        #pragma unroll
        for (int j = 0; j < 32; ++j) pf[j] = yb[j * Cc + lab];
        {
            float praw = pf[0];
            pf[0] = yb[32 * Cc + lab];
            lo = lane0 ? ((double)blankpf(praw) + DEPS) : 0.0;
            hi = lane0 ? ((double)praw + DEPS) : 0.0;
            #pragma unroll
            for (int j = 1; j < 32; ++j) {
                float r = pf[j];
                pf[j] = yb[(32 + j) * Cc + lab];
                dostep(r);
            }
            renorm();
        }
        #pragma unroll 1
        for (int g = 1; g < 7; ++g) {
            const float* ybg = yb + (size_t)(g * 32 + 32) * Cc;
            #pragma unroll
            for (int j = 0; j < 32; ++j) {
                float r = pf[j];
                pf[j] = ybg[j * Cc + lab];
                dostep(r);
            }
            renorm();
        }
        #pragma unroll
        for (int j = 0; j < 32; ++j) dostep(pf[j]);
        renorm();
    } else {
        auto dostep = [&](float praw) {
            double pb = (double)blankpf(praw) + DEPS;
            double ph = validhi ? ((double)praw + DEPS) : 0.0;
            double qlo = lo * pb;
            double qhi = hi * ph;
            double qlo_n = dpp64_shl1(qlo);
            double qhi_n = dpp64_shl1(qhi);
            double nb = skipN ? (qlo_n + qhi_n) : qlo_n;
            lo = qlo + qhi;
            hi = qhi + nb;
        };
        lo = (lane == 48) ? 1.0 : 0.0;
        hi = (lane == 47) ? 1.0 : 0.0;
        float pf[32];
        #pragma unroll
        for (int j = 0; j < 32; ++j) pf[j] = yb[(size_t)(511 - j) * Cc + lab];
        #pragma unroll 1
        for (int g = 0; g < 7; ++g) {
            #pragma unroll
            for (int j = 0; j < 32; ++j) {
                float r = pf[j];
                pf[j] = yb[(size_t)(511 - (g * 32 + 32 + j)) * Cc + lab];
                dostep(r);
            }
            renorm();
        }
        #pragma unroll
        for (int j = 0; j < 32; ++j) dostep(pf[j]);
        renorm();
        sblo[lane] = lo;
        sbhi[lane] = hi;
        sbc[lane]  = c;
    }

    __syncthreads();

    if (wave == 0) {
        double plo = lo * sblo[lane];
        double phi = hi * sbhi[lane];
        float ctot = (float)(c + sbc[lane]);
        float yl = log2d(plo) + ctot;
        float yh = log2d(phi) + ctot;
        float v = lae2(yl, yh);
        #pragma unroll
        for (int mk = 1; mk < 64; mk <<= 1)
            v = lae2(v, __shfl_xor(v, mk, 64));
        if (lane0) out[b] = -(v * LN2F);
    }
}

// ---------------------------------------------------------------- probe: full
__global__ __launch_bounds__(128)
void probe_full(const int* __restrict__ y_true,
                const float* __restrict__ y_pred,
                float* __restrict__ ws) {
    const int b = blockIdx.x;
    const int lane = threadIdx.x & 63;
    const int wave = threadIdx.x >> 6;
    const float* yb = y_pred + (size_t)b * Tc * Cc;

    const int lab = (lane < Lc) ? y_true[b * Lc + lane] : (Cc - 1);
    const int labm1 = __builtin_amdgcn_ds_bpermute(((lane + 63) & 63) << 2, lab);
    const int labp1 = __builtin_amdgcn_ds_bpermute(((lane + 1) & 63) << 2, lab);
    const bool skip  = (lab != (Cc - 1)) && (lab != labm1);
    const bool skipN = (labp1 != (Cc - 1)) && (labp1 != lab);
    const bool validhi = (lane < Lc);
    const bool lane0 = (lane == 0);

    float fres = 0.0f;
    #pragma unroll 1
    for (int rep = 0; rep < 4; ++rep) {
        double lo = 0.0, hi = 0.0;
        int c = 0;
        auto renorm = [&]() {
            double mx = fmax(lo, hi);
            #pragma unroll
            for (int mk = 1; mk < 64; mk <<= 1)
                mx = fmax(mx, __shfl_xor(mx, mk, 64));
            int e = (int)((__double_as_longlong(mx) >> 52) & 0x7FF) - 1023;
            double sc = __longlong_as_double((long long)(1023 - e) << 52);
            lo *= sc; hi *= sc;
            c += e;
        };
        if (wave == 0) {
            auto dostep = [&](float praw) {
                double pb = (double)blankpf(praw) + DEPS;
                double ph = validhi ? ((double)praw + DEPS) : 0.0;
                double sh = dpp64_shr1(hi);
                double a3 = skip ? sh : 0.0;
                double nlo = (lo + sh) * pb;
                double nhi = (hi + lo + a3) * ph;
                lo = nlo; hi = nhi;
            };
            float pf[32];
            #pragma unroll
            for (int j = 0; j < 32; ++j) pf[j] = yb[j * Cc + lab];
            pf[0] += (float)rep * 1e-35f;   // blocks cross-rep CSE; exact at runtime
            {
                float praw = pf[0];
                pf[0] = yb[32 * Cc + lab];
                lo = lane0 ? ((double)blankpf(praw) + DEPS) : 0.0;
                hi = lane0 ? ((double)praw + DEPS) : 0.0;
                #pragma unroll
                for (int j = 1; j < 32; ++j) {
                    float r = pf[j];
                    pf[j] = yb[(32 + j) * Cc + lab];
                    dostep(r);
                }
                renorm();
            }
            #pragma unroll 1
            for (int g = 1; g < 7; ++g) {
                const float* ybg = yb + (size_t)(g * 32 + 32) * Cc;
                #pragma unroll
                for (int j = 0; j < 32; ++j) {
                    float r = pf[j];
                    pf[j] = ybg[j * Cc + lab];
                    dostep(r);
                }
                renorm();
            }
            #pragma unroll
            for (int j = 0; j < 32; ++j) dostep(pf[j]);
            renorm();
        } else {
            auto dostep = [&](float praw) {
                double pb = (double)blankpf(praw) + DEPS;
                double ph = validhi ? ((double)praw + DEPS) : 0.0;
                double qlo = lo * pb;
                double qhi = hi * ph;
                double qlo_n = dpp64_shl1(qlo);
                double qhi_n = dpp64_shl1(qhi);
                double nb = skipN ? (qlo_n + qhi_n) : qlo_n;
                lo = qlo + qhi;
                hi = qhi + nb;
            };
            lo = (lane == 48) ? 1.0 + (double)rep * 1e-18 : 0.0;  // rep twist
            hi = (lane == 47) ? 1.0 : 0.0;
            float pf[32];
            #pragma unroll
            for (int j = 0; j < 32; ++j) pf[j] = yb[(size_t)(511 - j) * Cc + lab];
            #pragma unroll 1
            for (int g = 0; g < 7; ++g) {
                #pragma unroll
                for (int j = 0; j < 32; ++j) {
                    float r = pf[j];
                    pf[j] = yb[(size_t)(511 - (g * 32 + 32 + j)) * Cc + lab];
                    dostep(r);
                }
                renorm();
            }
            #pragma unroll
            for (int j = 0; j < 32; ++j) dostep(pf[j]);
            renorm();
        }
        fres += (float)lo + (float)hi + (float)c;
    }
    #pragma unroll
    for (int mk = 1; mk < 64; mk <<= 1) fres += __shfl_xor(fres, mk, 64);
    if (lane0) ws[b * 2 + wave] = fres;
}

// --------------------------------------------------------------- probe: chain
__global__ __launch_bounds__(128)
void probe_chain(const int* __restrict__ y_true,
                 const float* __restrict__ y_pred,
                 float* __restrict__ ws) {
    const int b = blockIdx.x;
    const int lane = threadIdx.x & 63;
    const int wave = threadIdx.x >> 6;

    const int lab = (lane < Lc) ? y_true[b * Lc + lane] : (Cc - 1);
    const int labm1 = __builtin_amdgcn_ds_bpermute(((lane + 63) & 63) << 2, lab);
    const int labp1 = __builtin_amdgcn_ds_bpermute(((lane + 1) & 63) << 2, lab);
    const bool skip  = (lab != (Cc - 1)) && (lab != labm1);
    const bool skipN = (labp1 != (Cc - 1)) && (labp1 != lab);
    const bool validhi = (lane < Lc);
    const bool lane0 = (lane == 0);

    float fres = 0.0f;
    #pragma unroll 1
    for (int rep = 0; rep < 4; ++rep) {
        double lo = 0.0, hi = 0.0;
        int c = 0;
        auto renorm = [&]() {
            double mx = fmax(lo, hi);
            #pragma unroll
            for (int mk = 1; mk < 64; mk <<= 1)
                mx = fmax(mx, __shfl_xor(mx, mk, 64));
            int e = (int)((__double_as_longlong(mx) >> 52) & 0x7FF) - 1023;
            double sc = __longlong_as_double((long long)(1023 - e) << 52);
            lo *= sc; hi *= sc;
            c += e;
        };
        if (wave == 0) {
            auto dostep = [&](float praw) {
                double pb = (double)blankpf(praw) + DEPS;
                double ph = validhi ? ((double)praw + DEPS) : 0.0;
                double sh = dpp64_shr1(hi);
                double a3 = skip ? sh : 0.0;
                double nlo = (lo + sh) * pb;
                double nhi = (hi + lo + a3) * ph;
                lo = nlo; hi = nhi;
            };
            {
                float praw = synthp(0, lane, rep);
                lo = lane0 ? ((double)blankpf(praw) + DEPS) : 0.0;
                hi = lane0 ? ((double)praw + DEPS) : 0.0;
            }
            #pragma unroll 1
            for (int g = 0; g < 8; ++g) {
                #pragma unroll
                for (int j = 0; j < 32; ++j) {
                    int t = g * 32 + j;
                    if (t == 0) continue;
                    dostep(synthp(t, lane, rep));
                }
                renorm();
            }
        } else {
            auto dostep = [&](float praw) {
                double pb = (double)blankpf(praw) + DEPS;
                double ph = validhi ? ((double)praw + DEPS) : 0.0;
                double qlo = lo * pb;
                double qhi = hi * ph;
                double qlo_n = dpp64_shl1(qlo);
                double qhi_n = dpp64_shl1(qhi);
                double nb = skipN ? (qlo_n + qhi_n) : qlo_n;
                lo = qlo + qhi;
                hi = qhi + nb;
            };
            lo = (lane == 48) ? 1.0 : 0.0;
            hi = (lane == 47) ? 1.0 : 0.0;
            #pragma unroll 1
            for (int g = 0; g < 8; ++g) {
                #pragma unroll
                for (int j = 0; j < 32; ++j)
                    dostep(synthp(511 - (g * 32 + j), lane, rep));
                renorm();
            }
        }
        fres += (float)lo + (float)hi + (float)c;
    }
    #pragma unroll
    for (int mk = 1; mk < 64; mk <<= 1) fres += __shfl_xor(fres, mk, 64);
    if (lane0) ws[b * 2 + wave] = fres;
}

// ---------------------------------------------------------------- probe: load
__global__ __launch_bounds__(128)
void probe_load(const int* __restrict__ y_true,
                const float* __restrict__ y_pred,
                float* __restrict__ ws) {
    const int b = blockIdx.x;
    const int lane = threadIdx.x & 63;
    const int wave = threadIdx.x >> 6;
    const float* yb = y_pred + (size_t)b * Tc * Cc;
    const int lab = (lane < Lc) ? y_true[b * Lc + lane] : (Cc - 1);

    float acc = 0.0f;
    #pragma unroll 1
    for (int rep = 0; rep < 4; ++rep) {
        acc += (float)rep * 1e-30f;
        float pf[32];
        if (wave == 0) {
            #pragma unroll
            for (int j = 0; j < 32; ++j) pf[j] = yb[j * Cc + lab];
            {
                float r = pf[0];
                pf[0] = yb[32 * Cc + lab];
                acc += r;
                #pragma unroll
                for (int j = 1; j < 32; ++j) {
                    float r2 = pf[j];
                    pf[j] = yb[(32 + j) * Cc + lab];
                    acc += r2;
                }
            }
            #pragma unroll 1
            for (int g = 1; g < 7; ++g) {
                const float* ybg = yb + (size_t)(g * 32 + 32) * Cc;
                #pragma unroll
                for (int j = 0; j < 32; ++j) {
                    float r = pf[j];
                    pf[j] = ybg[j * Cc + lab];
                    acc += r;
                }
            }
            #pragma unroll
            for (int j = 0; j < 32; ++j) acc += pf[j];
        } else {
            #pragma unroll
            for (int j = 0; j < 32; ++j) pf[j] = yb[(size_t)(511 - j) * Cc + lab];
            #pragma unroll 1
            for (int g = 0; g < 7; ++g) {
                #pragma unroll
                for (int j = 0; j < 32; ++j) {
                    float r = pf[j];
                    pf[j] = yb[(size_t)(511 - (g * 32 + 32 + j)) * Cc + lab];
                    acc += r;
                }
            }
            #pragma unroll
            for (int j = 0; j < 32; ++j) acc += pf[j];
        }
    }
    #pragma unroll
    for (int mk = 1; mk < 64; mk <<= 1) acc += __shfl_xor(acc, mk, 64);
    if (lane == 0) ws[b * 2 + wave] = acc;
}

extern "C" void kernel_launch(void* const* d_in, const int* in_sizes, int n_in,
                              void* d_out, int out_size, void* d_ws, size_t ws_size,
                              hipStream_t stream) {
    const int* y_true = (const int*)d_in[0];
    const float* y_pred = (const float*)d_in[1];
    float* out = (float*)d_out;
    float* wsf = (float*)d_ws;
    if (ws_size >= 16384) {
        hipLaunchKernelGGL(probe_full,  dim3(Bc), dim3(128), 0, stream, y_true, y_pred, wsf);
        hipLaunchKernelGGL(probe_chain, dim3(Bc), dim3(128), 0, stream, y_true, y_pred, wsf + 1024);
        hipLaunchKernelGGL(probe_load,  dim3(Bc), dim3(128), 0, stream, y_true, y_pred, wsf + 2048);
    }
    hipLaunchKernelGGL(ctc_fb_kernel, dim3(Bc), dim3(128), 0, stream,
                       y_true, y_pred, out);
}

// Round 16
// 28.972 us; speedup vs baseline: 9.8521x; 9.8521x over previous
//
#include <hip/hip_runtime.h>

// CTC batch cost, forward-backward split, f64 probability domain, wave-uniform
// power-of-2 renorm every 32 steps (bit-identical to round 11, which passed
// with absmax 0.0). Round-16 restructure for the in-order issue train:
//  - per-16-step batch phase precomputes pb64[16]/ph64[16] (readlane, +DEPS in
//    f64, validhi mask, cvt) OFF the serial chain, dense and independent;
//  - chain keeps only: dpp64 + select + 3 add_f64 + 2 mul_f64 per step;
//  - bwd chain uses nb = shl1(qlo + (skip ? qhi : 0)) == R11's
//    skipN?(qlo_n+qhi_n):qlo_n  (skipN_l == skip_{l+1}), halving bwd DPPs;
//  - renorm reduces the integer biased exponent (int shuffles, same e).
// Wave 0: forward alpha_255 (t=0..255). Wave 1: backward beta_255 (t=511..256).
// loglik = log2(sum_s alpha_255[s]*beta_255[s]) + ca + cb.

constexpr int Bc = 512, Tc = 512, Cc = 128, Lc = 48;
constexpr double DEPS = 1e-7;
constexpr float FNEG = -1e30f;
constexpr float LN2F = 0.69314718055994530942f;

#define DPP_WAVE_SHR1 0x138
#define DPP_WAVE_SHL1 0x130

__device__ __forceinline__ double dpp64_shr1(double x) {
    // lane l <- lane l-1; lane 0 <- 0.0
    long long u = __double_as_longlong(x);
    int a = __builtin_amdgcn_update_dpp(0, (int)u,         DPP_WAVE_SHR1, 0xF, 0xF, false);
    int b = __builtin_amdgcn_update_dpp(0, (int)(u >> 32), DPP_WAVE_SHR1, 0xF, 0xF, false);
    return __longlong_as_double(((long long)b << 32) | (unsigned int)a);
}
__device__ __forceinline__ double dpp64_shl1(double x) {
    // lane l <- lane l+1; lane 63 <- 0.0
    long long u = __double_as_longlong(x);
    int a = __builtin_amdgcn_update_dpp(0, (int)u,         DPP_WAVE_SHL1, 0xF, 0xF, false);
    int b = __builtin_amdgcn_update_dpp(0, (int)(u >> 32), DPP_WAVE_SHL1, 0xF, 0xF, false);
    return __longlong_as_double(((long long)b << 32) | (unsigned int)a);
}

__device__ __forceinline__ float lae2(float a, float b) {  // final reduce only
    float m = fmaxf(a, b);
    float d = fabsf(a - b);
    return m + __log2f(1.0f + __builtin_amdgcn_exp2f(-d));
}
__device__ __forceinline__ float rd63f(float v) {
    return __uint_as_float((unsigned)
        __builtin_amdgcn_readlane(__float_as_uint(v), 63));
}
__device__ __forceinline__ float log2d(double x) {
    if (!(x > 0.0)) return FNEG;
    long long u = __double_as_longlong(x);
    int e = (int)((u >> 52) & 0x7FF);
    if (e == 0) return FNEG;
    double m = __longlong_as_double((u & 0x000FFFFFFFFFFFFFLL) | 0x3FF0000000000000LL);
    return __log2f((float)m) + (float)(e - 1023);
}

__global__ __launch_bounds__(128)
void ctc_fb_kernel(const int* __restrict__ y_true,
                   const float* __restrict__ y_pred,
                   float* __restrict__ out) {
    const int b = blockIdx.x;
    const int lane = threadIdx.x & 63;
    const int wave = threadIdx.x >> 6;

    const float* yb = y_pred + (size_t)b * Tc * Cc;

    const int lab = (lane < Lc) ? y_true[b * Lc + lane] : (Cc - 1);
    const int labm1 = __builtin_amdgcn_ds_bpermute(((lane + 63) & 63) << 2, lab);
    const bool skip  = (lab != (Cc - 1)) && (lab != labm1);   // into 2l+1 from 2l-1
    const bool validhi = (lane < Lc);
    const bool lane0 = (lane == 0);

    __shared__ double sblo[64], sbhi[64];
    __shared__ int sbc[64];

    double lo = 0.0, hi = 0.0;
    int c = 0;   // wave-uniform log2 scale (exact integer)

    auto renorm = [&]() {
        // wave-uniform e = exponent of wave-max value; reduce the INT biased
        // exponent (monotone in value) -> same e as R11's f64-max reduce.
        double mx = fmax(lo, hi);
        int eb = (int)((__double_as_longlong(mx) >> 52) & 0x7FF);
        #pragma unroll
        for (int mk = 1; mk < 64; mk <<= 1)
            eb = max(eb, __shfl_xor(eb, mk, 64));
        int e = eb - 1023;
        double sc = __longlong_as_double((long long)(1023 - e) << 52);  // exact 2^-e
        lo *= sc; hi *= sc;
        c += e;
    };

    float praw[16];
    double pb64[16], ph64[16];

    auto batch = [&]() {   // off-chain: per-step probs in f64 (bit-identical to R11)
        #pragma unroll
        for (int j = 0; j < 16; ++j) {
            pb64[j] = (double)rd63f(praw[j]) + DEPS;
            ph64[j] = validhi ? ((double)praw[j] + DEPS) : 0.0;
        }
    };

    if (wave == 0) {
        // -------- forward: alpha_255, consume p_0..p_255 --------
        auto step = [&](int j) {
            double sh = dpp64_shr1(hi);            // alpha[2l-1]
            double a3 = skip ? sh : 0.0;
            double nlo = (lo + sh) * pb64[j];      // even state (blank)
            double nhi = ((hi + lo) + a3) * ph64[j];  // odd state (label)
            lo = nlo; hi = nhi;
        };
        #pragma unroll
        for (int j = 0; j < 16; ++j) praw[j] = yb[j * Cc + lab];
        {   // group 0 (t=0..15), init at t=0
            batch();
            const float* ybn = yb + (size_t)16 * Cc + lab;
            #pragma unroll
            for (int j = 0; j < 16; ++j) praw[j] = ybn[(size_t)j * Cc];
            lo = lane0 ? pb64[0] : 0.0;   // state 0 = blank
            hi = lane0 ? ph64[0] : 0.0;   // state 1 = label[0]
            #pragma unroll
            for (int j = 1; j < 16; ++j) step(j);
        }
        #pragma unroll 1
        for (int g = 1; g < 16; ++g) {
            batch();
            if (g < 15) {
                const float* ybn = yb + (size_t)((g + 1) * 16) * Cc + lab;
                #pragma unroll
                for (int j = 0; j < 16; ++j) praw[j] = ybn[(size_t)j * Cc];
            }
            #pragma unroll
            for (int j = 0; j < 16; ++j) step(j);
            if (g & 1) renorm();          // every 32 steps, same points as R11
        }
    } else {
        // -------- backward: beta_255, consume p_511..p_256 --------
        // q[s] = beta_{t+1}[s] * p_{t+1}[s]
        // beta_t[2l]   = q[2l] + q[2l+1]
        // beta_t[2l+1] = q[2l+1] + shl1( q[2l] + (skip ? q[2l+1] : 0) )
        auto step = [&](int j) {
            double qlo = lo * pb64[j];             // q[2l]
            double qhi = hi * ph64[j];             // q[2l+1]
            double u  = qlo + (skip ? qhi : 0.0);  // lane l+1's contribution source
            double nb = dpp64_shl1(u);
            lo = qlo + qhi;
            hi = qhi + nb;
        };
        lo = (lane == 48) ? 1.0 : 0.0;    // beta_511: state 96
        hi = (lane == 47) ? 1.0 : 0.0;    // beta_511: state 95
        #pragma unroll
        for (int j = 0; j < 16; ++j) praw[j] = yb[(size_t)(511 - j) * Cc + lab];
        #pragma unroll 1
        for (int g = 0; g < 16; ++g) {
            batch();
            if (g < 15) {
                const float* ybn = yb + lab;
                const int t0 = 511 - (g + 1) * 16;
                #pragma unroll
                for (int j = 0; j < 16; ++j) praw[j] = ybn[(size_t)(t0 - j) * Cc];
            }
            #pragma unroll
            for (int j = 0; j < 16; ++j) step(j);
            if (g & 1) renorm();          // every 32 steps, same points as R11
        }
        sblo[lane] = lo;
        sbhi[lane] = hi;
        sbc[lane]  = c;
    }

    __syncthreads();

    if (wave == 0) {
        // loglik = log2( sum_s alpha_255[s]*beta_255[s] ) + ca + cb
        double plo = lo * sblo[lane];
        double phi = hi * sbhi[lane];
        float ctot = (float)(c + sbc[lane]);
        float yl = log2d(plo) + ctot;
        float yh = log2d(phi) + ctot;
        float v = lae2(yl, yh);
        #pragma unroll
        for (int mk = 1; mk < 64; mk <<= 1)
            v = lae2(v, __shfl_xor(v, mk, 64));
        if (lane0) out[b] = -(v * LN2F);
    }
}

extern "C" void kernel_launch(void* const* d_in, const int* in_sizes, int n_in,
                              void* d_out, int out_size, void* d_ws, size_t ws_size,
                              hipStream_t stream) {
    const int* y_true = (const int*)d_in[0];
    const float* y_pred = (const float*)d_in[1];
    float* out = (float*)d_out;
    hipLaunchKernelGGL(ctc_fb_kernel, dim3(Bc), dim3(128), 0, stream,
                       y_true, y_pred, out);
}